// Round 2
// baseline (6192.471 us; speedup 1.0000x reference)
//
#include <hip/hip_runtime.h>
#include <hip/hip_fp16.h>
#include <math.h>

// Problem constants (reference: B=512, S=512, D_IN=D_OUT=256, fp32)
#define S_LEN 512
#define B_SZ  512
#define D_DIM 256

// Fast, robust tanh: 1 - 2/(e^{2x}+1). Abs err ~1e-6, correct at +-inf.
__device__ __forceinline__ float tanh_fast(float x) {
    float e = __expf(2.0f * x);
    return 1.0f - 2.0f / (e + 1.0f);
}

// ---------------------------------------------------------------------------
// Phase 0: Wh fp32 -> fp16 into workspace (weights are the whole phase-2
// stream; halving bytes halves the per-CU L2 floor). 8 elems/thread.
// ---------------------------------------------------------------------------
__global__ __launch_bounds__(256) void convert_wh(const float* __restrict__ Wh,
                                                  __half* __restrict__ Whh) {
    size_t i = ((size_t)blockIdx.x * 256 + threadIdx.x) * 8;
    float4 a = *(const float4*)(Wh + i);
    float4 b = *(const float4*)(Wh + i + 4);
    __half2 o[4];
    o[0] = __floats2half2_rn(a.x, a.y);
    o[1] = __floats2half2_rn(a.z, a.w);
    o[2] = __floats2half2_rn(b.x, b.y);
    o[3] = __floats2half2_rn(b.z, b.w);
    *(uint4*)(Whh + i) = *(const uint4*)o;
}

// ---------------------------------------------------------------------------
// Phase 1: Z[b,t,:] = x[b,t,:] @ Wx[t]   (Z written into d_out, fp32)
// grid (S, B/16), block 256. Thread j owns output column j for 16 batch rows.
// x[(b0+r), t, k] is wave-uniform -> compiler emits s_load (SGPR operand),
// so the inner loop is pure v_fma with no LDS traffic. FMA-bound:
// 16*256*256/128 = 8192 cyc/block, 64 blocks/CU -> ~240 us floor.
// ---------------------------------------------------------------------------
__global__ __launch_bounds__(256) void phase1_xwx(const float* __restrict__ x,
                                                  const float* __restrict__ Wx,
                                                  float* __restrict__ Z) {
    const int t  = blockIdx.x;
    const int b0 = blockIdx.y * 16;
    const int j  = threadIdx.x;

    float acc[16];
    #pragma unroll
    for (int r = 0; r < 16; ++r) acc[r] = 0.0f;

    const float* wp = Wx + (size_t)t * D_DIM * D_DIM + j;
    const float* xp = x + ((size_t)b0 * S_LEN + t) * D_DIM;  // + r*S_LEN*D_DIM + k

    #pragma unroll 4
    for (int k = 0; k < D_DIM; ++k) {
        float w = wp[(size_t)k * D_DIM];   // coalesced: j consecutive across lanes
        #pragma unroll
        for (int r = 0; r < 16; ++r)
            acc[r] = fmaf(xp[(size_t)r * S_LEN * D_DIM + k], w, acc[r]);
    }

    float* zp = Z + ((size_t)b0 * S_LEN + t) * D_DIM + j;
    #pragma unroll
    for (int r = 0; r < 16; ++r) zp[(size_t)r * S_LEN * D_DIM] = acc[r];
}

// ---------------------------------------------------------------------------
// Phase 2: sequential scan. Block g owns batches 2g..2g+1, loops t privately
// (recurrence independent per batch => no grid sync). 256 blocks -> every CU
// busy; 512 threads (8 waves) for memory-level parallelism.
// Mapping: c4=(tid&63)*4 -> 4 cols; ks=tid>>6 -> 32-wide k-slice (wave-
// uniform). Reduction + tanh spread across ALL threads (row=tid>>8,
// col=tid&255), not one wave.
// ---------------------------------------------------------------------------
__device__ __forceinline__ float4 load_w4(const float* p) { return *(const float4*)p; }
__device__ __forceinline__ float4 load_w4(const __half* p) {
    uint2 u = *(const uint2*)p;          // one global_load_dwordx2 (8 B)
    __half2 ab = *(const __half2*)&u.x;
    __half2 cd = *(const __half2*)&u.y;
    float2 f0 = __half22float2(ab);
    float2 f1 = __half22float2(cd);
    return make_float4(f0.x, f0.y, f1.x, f1.y);
}

template <typename WT>
__global__ __launch_bounds__(512) void phase2_scan(const WT* __restrict__ Wh,
                                                   float* __restrict__ ZH) {
    const int b0  = blockIdx.x * 2;
    const int tid = threadIdx.x;
    const int c4  = (tid & 63) * 4;   // column base for partials
    const int ks  = tid >> 6;         // k-slice 0..7 (wave-uniform)
    const int row = tid >> 8;         // 0..1  (reduce phase)
    const int col = tid & 255;        //       (reduce phase)

    __shared__ float h[2][D_DIM];         // 2 KB hidden state
    __shared__ float red[8][2][D_DIM];    // 16 KB partial sums

    ((float*)h)[tid] = 0.0f;              // h_{-1} = 0 (512 floats, 512 thr)
    __syncthreads();

    float* zrow = ZH + ((size_t)(b0 + row) * S_LEN) * D_DIM + col;

    for (int t = 0; t < S_LEN; ++t) {
        // z prefetch: independent of h, overlaps the k-loop.
        float zv = zrow[(size_t)t * D_DIM];

        float4 a0 = make_float4(0.f, 0.f, 0.f, 0.f);
        float4 a1 = make_float4(0.f, 0.f, 0.f, 0.f);
        const WT* wp = Wh + (size_t)t * D_DIM * D_DIM + c4;
        const int kb = ks * 32;
        #pragma unroll 8
        for (int kk = 0; kk < 32; ++kk) {
            const int k = kb + kk;
            // lanes: consecutive c4 -> contiguous coalesced load
            float4 w = load_w4(wp + (size_t)k * D_DIM);
            float h0 = h[0][k];   // k wave-uniform -> LDS broadcast (free)
            float h1 = h[1][k];
            a0.x = fmaf(h0, w.x, a0.x);
            a0.y = fmaf(h0, w.y, a0.y);
            a0.z = fmaf(h0, w.z, a0.z);
            a0.w = fmaf(h0, w.w, a0.w);
            a1.x = fmaf(h1, w.x, a1.x);
            a1.y = fmaf(h1, w.y, a1.y);
            a1.z = fmaf(h1, w.z, a1.z);
            a1.w = fmaf(h1, w.w, a1.w);
        }
        *(float4*)&red[ks][0][c4] = a0;
        *(float4*)&red[ks][1][c4] = a1;
        __syncthreads();

        // Each thread finishes exactly one output element (row, col).
        float s = zv;
        #pragma unroll
        for (int u = 0; u < 8; ++u) s += red[u][row][col];  // col consec -> no conflicts
        float hv = tanh_fast(s);
        h[row][col] = hv;                 // next-step state
        zrow[(size_t)t * D_DIM] = hv;     // output over Z (coalesced)
        __syncthreads();                  // h visible before next k-loop
    }
}

// ---------------------------------------------------------------------------
extern "C" void kernel_launch(void* const* d_in, const int* in_sizes, int n_in,
                              void* d_out, int out_size, void* d_ws, size_t ws_size,
                              hipStream_t stream) {
    const float* x  = (const float*)d_in[0];   // [B, S, D_IN]
    const float* Wx = (const float*)d_in[1];   // [S, D_IN, D_OUT]
    const float* Wh = (const float*)d_in[2];   // [S, D_OUT, D_OUT]
    float* out = (float*)d_out;                // [B, S, D_OUT]

    // Phase 1: Z = batched x @ Wx -> d_out
    phase1_xwx<<<dim3(S_LEN, B_SZ / 16), 256, 0, stream>>>(x, Wx, out);

    const size_t whh_bytes = (size_t)S_LEN * D_DIM * D_DIM * sizeof(__half);
    if (ws_size >= whh_bytes) {
        // Phase 0: Wh -> fp16 (halves the sequential-phase weight stream)
        __half* Whh = (__half*)d_ws;
        convert_wh<<<(S_LEN * D_DIM * D_DIM) / (256 * 8), 256, 0, stream>>>(Wh, Whh);
        phase2_scan<__half><<<B_SZ / 2, 512, 0, stream>>>(Whh, out);
    } else {
        phase2_scan<float><<<B_SZ / 2, 512, 0, stream>>>(Wh, out);
    }
}